// Round 1
// baseline (513.978 us; speedup 1.0000x reference)
//
#include <hip/hip_runtime.h>
#include <hip/hip_bf16.h>

typedef short bf16x8 __attribute__((ext_vector_type(8)));
typedef float f32x4 __attribute__((ext_vector_type(4)));

#define N_B 4
#define N_T 2048
#define N_D 1024
#define N_H 16
#define N_DH 64

__device__ __forceinline__ unsigned short f2bf(float f) {
  union { float f; unsigned int u; } c; c.f = f;
  unsigned int u = c.u;
  return (unsigned short)((u + 0x7FFFu + ((u >> 16) & 1u)) >> 16);
}

// ---------------------------------------------------------------- cast weights
__global__ void cast_w(const float* __restrict__ w0, const float* __restrict__ w1,
                       const float* __restrict__ w2, const float* __restrict__ w3,
                       unsigned short* __restrict__ dst) {
  const int z = blockIdx.z;
  const float* src = (z == 0) ? w0 : (z == 1) ? w1 : (z == 2) ? w2 : w3;
  unsigned short* d = dst + (size_t)z * (N_D * N_D);
  const int i = (blockIdx.x * 256 + threadIdx.x) * 8;
  float4 a = *(const float4*)(src + i);
  float4 b = *(const float4*)(src + i + 4);
  bf16x8 p;
  p[0] = (short)f2bf(a.x); p[1] = (short)f2bf(a.y);
  p[2] = (short)f2bf(a.z); p[3] = (short)f2bf(a.w);
  p[4] = (short)f2bf(b.x); p[5] = (short)f2bf(b.y);
  p[6] = (short)f2bf(b.z); p[7] = (short)f2bf(b.w);
  *(bf16x8*)(d + i) = p;
}

// ------------------------------------------------- qkv projection GEMM (fp32 A)
// y = x @ W.T ; x [8192,1024] fp32, W [1024,1024] bf16 rows are the N dim.
// out: per-head layout [B,H,T,DH] bf16.
__launch_bounds__(256, 2)
__global__ void proj_qkv(const float* __restrict__ qi, const float* __restrict__ ki,
                         const float* __restrict__ vi,
                         const unsigned short* __restrict__ wq,
                         const unsigned short* __restrict__ wk,
                         const unsigned short* __restrict__ wv,
                         unsigned short* __restrict__ qh,
                         unsigned short* __restrict__ kh,
                         unsigned short* __restrict__ vh) {
  const int z = blockIdx.z;
  const float* X = (z == 0) ? qi : (z == 1) ? ki : vi;
  const unsigned short* W = (z == 0) ? wq : (z == 1) ? wk : wv;
  unsigned short* O = (z == 0) ? qh : (z == 1) ? kh : vh;

  __shared__ unsigned short lds_a[128 * 40];  // rows padded to 40 elems
  __shared__ unsigned short lds_b[128 * 40];

  const int tid = threadIdx.x;
  const int wave = tid >> 6, lane = tid & 63;
  const int wm = wave >> 1, wn = wave & 1;
  const int lr = lane & 15, lg = lane >> 4;
  const int m0 = blockIdx.y * 128, n0 = blockIdx.x * 128;

  const int sr = tid >> 1;           // staging row 0..127
  const int sc = (tid & 1) * 16;     // staging col {0,16}

  f32x4 acc[4][4] = {};

  for (int k0 = 0; k0 < N_D; k0 += 32) {
    // stage A: fp32 -> bf16
    {
      const float* src = X + (size_t)(m0 + sr) * N_D + k0 + sc;
      float4 f0 = ((const float4*)src)[0];
      float4 f1 = ((const float4*)src)[1];
      float4 f2 = ((const float4*)src)[2];
      float4 f3 = ((const float4*)src)[3];
      bf16x8 p0, p1;
      p0[0]=(short)f2bf(f0.x); p0[1]=(short)f2bf(f0.y); p0[2]=(short)f2bf(f0.z); p0[3]=(short)f2bf(f0.w);
      p0[4]=(short)f2bf(f1.x); p0[5]=(short)f2bf(f1.y); p0[6]=(short)f2bf(f1.z); p0[7]=(short)f2bf(f1.w);
      p1[0]=(short)f2bf(f2.x); p1[1]=(short)f2bf(f2.y); p1[2]=(short)f2bf(f2.z); p1[3]=(short)f2bf(f2.w);
      p1[4]=(short)f2bf(f3.x); p1[5]=(short)f2bf(f3.y); p1[6]=(short)f2bf(f3.z); p1[7]=(short)f2bf(f3.w);
      *(bf16x8*)&lds_a[sr * 40 + sc]     = p0;
      *(bf16x8*)&lds_a[sr * 40 + sc + 8] = p1;
    }
    // stage B: bf16 copy
    {
      const unsigned short* src = W + (size_t)(n0 + sr) * N_D + k0 + sc;
      *(bf16x8*)&lds_b[sr * 40 + sc]     = *(const bf16x8*)src;
      *(bf16x8*)&lds_b[sr * 40 + sc + 8] = *(const bf16x8*)(src + 8);
    }
    __syncthreads();

    bf16x8 af[4], bfr[4];
#pragma unroll
    for (int m = 0; m < 4; ++m)
      af[m] = *(bf16x8*)&lds_a[(wm * 64 + m * 16 + lr) * 40 + lg * 8];
#pragma unroll
    for (int n = 0; n < 4; ++n)
      bfr[n] = *(bf16x8*)&lds_b[(wn * 64 + n * 16 + lr) * 40 + lg * 8];
#pragma unroll
    for (int m = 0; m < 4; ++m)
#pragma unroll
      for (int n = 0; n < 4; ++n)
        acc[m][n] = __builtin_amdgcn_mfma_f32_16x16x32_bf16(af[m], bfr[n], acc[m][n], 0, 0, 0);
    __syncthreads();
  }

  // epilogue: write [B,H,T,DH] bf16
#pragma unroll
  for (int m = 0; m < 4; ++m)
#pragma unroll
    for (int n = 0; n < 4; ++n)
#pragma unroll
      for (int r = 0; r < 4; ++r) {
        int row = m0 + wm * 64 + m * 16 + lg * 4 + r;   // global token row (b*T+t)
        int col = n0 + wn * 64 + n * 16 + lr;           // output feature
        int b = row >> 11, t = row & (N_T - 1);
        int hh = col >> 6, dh = col & 63;
        O[(((size_t)(b * N_H + hh)) * N_T + t) * N_DH + dh] = f2bf(acc[m][n][r]);
      }
}

// ------------------------------------------------------ output projection GEMM
__launch_bounds__(256, 2)
__global__ void proj_out(const unsigned short* __restrict__ A,
                         const unsigned short* __restrict__ W,
                         float* __restrict__ out) {
  __shared__ unsigned short lds_a[128 * 40];
  __shared__ unsigned short lds_b[128 * 40];

  const int tid = threadIdx.x;
  const int wave = tid >> 6, lane = tid & 63;
  const int wm = wave >> 1, wn = wave & 1;
  const int lr = lane & 15, lg = lane >> 4;
  const int m0 = blockIdx.y * 128, n0 = blockIdx.x * 128;

  const int sr = tid >> 1;
  const int sc = (tid & 1) * 16;

  f32x4 acc[4][4] = {};

  for (int k0 = 0; k0 < N_D; k0 += 32) {
    {
      const unsigned short* src = A + (size_t)(m0 + sr) * N_D + k0 + sc;
      *(bf16x8*)&lds_a[sr * 40 + sc]     = *(const bf16x8*)src;
      *(bf16x8*)&lds_a[sr * 40 + sc + 8] = *(const bf16x8*)(src + 8);
    }
    {
      const unsigned short* src = W + (size_t)(n0 + sr) * N_D + k0 + sc;
      *(bf16x8*)&lds_b[sr * 40 + sc]     = *(const bf16x8*)src;
      *(bf16x8*)&lds_b[sr * 40 + sc + 8] = *(const bf16x8*)(src + 8);
    }
    __syncthreads();

    bf16x8 af[4], bfr[4];
#pragma unroll
    for (int m = 0; m < 4; ++m)
      af[m] = *(bf16x8*)&lds_a[(wm * 64 + m * 16 + lr) * 40 + lg * 8];
#pragma unroll
    for (int n = 0; n < 4; ++n)
      bfr[n] = *(bf16x8*)&lds_b[(wn * 64 + n * 16 + lr) * 40 + lg * 8];
#pragma unroll
    for (int m = 0; m < 4; ++m)
#pragma unroll
      for (int n = 0; n < 4; ++n)
        acc[m][n] = __builtin_amdgcn_mfma_f32_16x16x32_bf16(af[m], bfr[n], acc[m][n], 0, 0, 0);
    __syncthreads();
  }

#pragma unroll
  for (int m = 0; m < 4; ++m)
#pragma unroll
    for (int n = 0; n < 4; ++n)
#pragma unroll
      for (int r = 0; r < 4; ++r) {
        int row = m0 + wm * 64 + m * 16 + lg * 4 + r;
        int col = n0 + wn * 64 + n * 16 + lr;
        out[(size_t)row * N_D + col] = acc[m][n][r];
      }
}

// ----------------------------------------------------------- flash attention
// Per block: one (b,h), 64 q rows. 4 waves x 16 q-rows each.
__launch_bounds__(256, 2)
__global__ void attn(const unsigned short* __restrict__ qh,
                     const unsigned short* __restrict__ kh,
                     const unsigned short* __restrict__ vh,
                     unsigned short* __restrict__ att) {
  __shared__ unsigned short k_lds[64 * 72];
  __shared__ unsigned short v_t[64 * 72];   // transposed: [d][key]
  __shared__ unsigned short p_lds[64 * 72]; // 4 waves x 16 rows

  const int tid = threadIdx.x;
  const int wave = tid >> 6, lane = tid & 63;
  const int lr = lane & 15, lg = lane >> 4;
  const int qt = blockIdx.x;           // q tile (64 rows)
  const int bh = blockIdx.y;           // b*16 + h
  const int q0 = qt * 64;

  const size_t base = (size_t)bh * N_T * N_DH;
  const unsigned short* Q = qh + base;
  const unsigned short* K = kh + base;
  const unsigned short* V = vh + base;

  // Q fragments: wave's 16 rows, K-dim = 64 (2 mfma halves)
  bf16x8 aq[2];
  {
    int qrow = q0 + wave * 16 + lr;
    aq[0] = *(const bf16x8*)&Q[(size_t)qrow * N_DH + lg * 8];
    aq[1] = *(const bf16x8*)&Q[(size_t)qrow * N_DH + lg * 8 + 32];
  }

  float m_r[4], l_r[4];
  f32x4 o_acc[4] = {};
#pragma unroll
  for (int r = 0; r < 4; ++r) { m_r[r] = -INFINITY; l_r[r] = 0.f; }

  const int sr = tid >> 2;           // staging key/row 0..63
  const int sc = (tid & 3) * 16;     // staging col {0,16,32,48}

  for (int kt = 0; kt <= qt; ++kt) {
    __syncthreads();   // protect k_lds/v_t reads of previous iteration
    // stage K tile [64 keys][64 d]
    {
      const unsigned short* src = K + (size_t)(kt * 64 + sr) * N_DH + sc;
      *(bf16x8*)&k_lds[sr * 72 + sc]     = *(const bf16x8*)src;
      *(bf16x8*)&k_lds[sr * 72 + sc + 8] = *(const bf16x8*)(src + 8);
    }
    // stage V transposed: v_t[d][key]
    {
      const unsigned short* src = V + (size_t)(kt * 64 + sr) * N_DH + sc;
      bf16x8 v0 = *(const bf16x8*)src;
      bf16x8 v1 = *(const bf16x8*)(src + 8);
#pragma unroll
      for (int j = 0; j < 8; ++j) {
        v_t[(sc + j) * 72 + sr]     = (unsigned short)v0[j];
        v_t[(sc + 8 + j) * 72 + sr] = (unsigned short)v1[j];
      }
    }
    __syncthreads();

    // S = Q @ K^T for this wave's 16 rows x 64 keys
    f32x4 s[4] = {};
#pragma unroll
    for (int n = 0; n < 4; ++n) {
      bf16x8 kb0 = *(bf16x8*)&k_lds[(n * 16 + lr) * 72 + lg * 8];
      bf16x8 kb1 = *(bf16x8*)&k_lds[(n * 16 + lr) * 72 + lg * 8 + 32];
      s[n] = __builtin_amdgcn_mfma_f32_16x16x32_bf16(aq[0], kb0, s[n], 0, 0, 0);
      s[n] = __builtin_amdgcn_mfma_f32_16x16x32_bf16(aq[1], kb1, s[n], 0, 0, 0);
    }

    // scale + causal mask + online softmax
    float pv[4][4], mrow[4];
#pragma unroll
    for (int r = 0; r < 4; ++r) mrow[r] = -INFINITY;
#pragma unroll
    for (int n = 0; n < 4; ++n)
#pragma unroll
      for (int r = 0; r < 4; ++r) {
        float val = s[n][r] * 0.125f;
        int key = kt * 64 + n * 16 + lr;
        int qr = q0 + wave * 16 + lg * 4 + r;
        if (key > qr) val = -INFINITY;
        pv[n][r] = val;
        mrow[r] = fmaxf(mrow[r], val);
      }
#pragma unroll
    for (int off = 1; off < 16; off <<= 1)
#pragma unroll
      for (int r = 0; r < 4; ++r) mrow[r] = fmaxf(mrow[r], __shfl_xor(mrow[r], off));

    float al[4];
#pragma unroll
    for (int r = 0; r < 4; ++r) {
      float mn = fmaxf(m_r[r], mrow[r]);
      al[r] = __expf(m_r[r] - mn);
      m_r[r] = mn;
    }
    float rs[4] = {0.f, 0.f, 0.f, 0.f};
#pragma unroll
    for (int n = 0; n < 4; ++n)
#pragma unroll
      for (int r = 0; r < 4; ++r) {
        float p = __expf(pv[n][r] - m_r[r]);
        pv[n][r] = p;
        rs[r] += p;
      }
#pragma unroll
    for (int off = 1; off < 16; off <<= 1)
#pragma unroll
      for (int r = 0; r < 4; ++r) rs[r] += __shfl_xor(rs[r], off);
#pragma unroll
    for (int r = 0; r < 4; ++r) l_r[r] = l_r[r] * al[r] + rs[r];
#pragma unroll
    for (int nd = 0; nd < 4; ++nd)
#pragma unroll
      for (int r = 0; r < 4; ++r) o_acc[nd][r] *= al[r];

    // P -> wave-private LDS (C-layout -> A-layout)
#pragma unroll
    for (int n = 0; n < 4; ++n)
#pragma unroll
      for (int r = 0; r < 4; ++r)
        p_lds[(wave * 16 + lg * 4 + r) * 72 + n * 16 + lr] = f2bf(pv[n][r]);

    // O += P @ V
#pragma unroll
    for (int kk = 0; kk < 2; ++kk) {
      bf16x8 pa = *(bf16x8*)&p_lds[(wave * 16 + lr) * 72 + lg * 8 + kk * 32];
#pragma unroll
      for (int nd = 0; nd < 4; ++nd) {
        bf16x8 vb = *(bf16x8*)&v_t[(nd * 16 + lr) * 72 + lg * 8 + kk * 32];
        o_acc[nd] = __builtin_amdgcn_mfma_f32_16x16x32_bf16(pa, vb, o_acc[nd], 0, 0, 0);
      }
    }
  }

  // epilogue: att[b, t, h*64+d] bf16
  const int b = bh >> 4, h = bh & 15;
  float inv[4];
#pragma unroll
  for (int r = 0; r < 4; ++r) inv[r] = 1.0f / l_r[r];
#pragma unroll
  for (int nd = 0; nd < 4; ++nd)
#pragma unroll
    for (int r = 0; r < 4; ++r) {
      int t_row = q0 + wave * 16 + lg * 4 + r;
      att[((size_t)(b * N_T + t_row)) * N_D + h * 64 + nd * 16 + lr] =
          f2bf(o_acc[nd][r] * inv[r]);
    }
}

// ---------------------------------------------------------------------- launch
extern "C" void kernel_launch(void* const* d_in, const int* in_sizes, int n_in,
                              void* d_out, int out_size, void* d_ws, size_t ws_size,
                              hipStream_t stream) {
  (void)in_sizes; (void)n_in; (void)out_size; (void)ws_size;
  const float* q  = (const float*)d_in[0];
  const float* k  = (const float*)d_in[1];
  const float* v  = (const float*)d_in[2];
  const float* wq = (const float*)d_in[3];
  const float* wk = (const float*)d_in[4];
  const float* wv = (const float*)d_in[5];
  const float* wo = (const float*)d_in[6];
  float* out = (float*)d_out;

  char* ws = (char*)d_ws;
  const size_t W_ELEMS = (size_t)N_D * N_D;           // 1048576
  const size_t T_ELEMS = (size_t)N_B * N_T * N_D;     // 8388608
  unsigned short* wqb = (unsigned short*)ws;
  unsigned short* wkb = wqb + W_ELEMS;
  unsigned short* wvb = wkb + W_ELEMS;
  unsigned short* wob = wvb + W_ELEMS;
  unsigned short* qhb = wob + W_ELEMS;
  unsigned short* khb = qhb + T_ELEMS;
  unsigned short* vhb = khb + T_ELEMS;
  unsigned short* att = vhb + T_ELEMS;

  cast_w<<<dim3(512, 1, 4), 256, 0, stream>>>(wq, wk, wv, wo, wqb);
  proj_qkv<<<dim3(8, 64, 3), 256, 0, stream>>>(q, k, v, wqb, wkb, wvb, qhb, khb, vhb);
  attn<<<dim3(N_T / 64, N_B * N_H), 256, 0, stream>>>(qhb, khb, vhb, att);
  proj_out<<<dim3(8, 64), 256, 0, stream>>>(att, wob, out);
}

// Round 2
// 285.744 us; speedup vs baseline: 1.7987x; 1.7987x over previous
//
#include <hip/hip_runtime.h>
#include <hip/hip_bf16.h>

typedef short bf16x8 __attribute__((ext_vector_type(8)));
typedef float f32x4 __attribute__((ext_vector_type(4)));

#define N_B 4
#define N_T 2048
#define N_D 1024
#define N_H 16
#define N_DH 64

__device__ __forceinline__ unsigned short f2bf(float f) {
  union { float f; unsigned int u; } c; c.f = f;
  unsigned int u = c.u;
  return (unsigned short)((u + 0x7FFFu + ((u >> 16) & 1u)) >> 16);
}

// async global->LDS, 16B per lane (dest must be linear: wave base + lane*16)
__device__ __forceinline__ void gll16(const unsigned short* g, unsigned short* l) {
  __builtin_amdgcn_global_load_lds(
      (const __attribute__((address_space(1))) unsigned int*)(const void*)g,
      (__attribute__((address_space(3))) unsigned int*)(void*)l, 16, 0, 0);
}

// ---------------------------------------------------------------- cast weights
__global__ void cast_w(const float* __restrict__ w0, const float* __restrict__ w1,
                       const float* __restrict__ w2, const float* __restrict__ w3,
                       unsigned short* __restrict__ dst) {
  const int z = blockIdx.z;
  const float* src = (z == 0) ? w0 : (z == 1) ? w1 : (z == 2) ? w2 : w3;
  unsigned short* d = dst + (size_t)z * (N_D * N_D);
  const int i = (blockIdx.x * 256 + threadIdx.x) * 8;
  float4 a = *(const float4*)(src + i);
  float4 b = *(const float4*)(src + i + 4);
  bf16x8 p;
  p[0] = (short)f2bf(a.x); p[1] = (short)f2bf(a.y);
  p[2] = (short)f2bf(a.z); p[3] = (short)f2bf(a.w);
  p[4] = (short)f2bf(b.x); p[5] = (short)f2bf(b.y);
  p[6] = (short)f2bf(b.z); p[7] = (short)f2bf(b.w);
  *(bf16x8*)(d + i) = p;
}

// ------------------------------------------------- qkv projection GEMM (fp32 A)
// y = x @ W.T ; A reg-staged (fp32->bf16 cast), B via global_load_lds.
// q,k outputs: [B,H,T,DH] bf16 ; v output: TRANSPOSED [B,H,DH,T] bf16.
__launch_bounds__(256, 2)
__global__ void proj_qkv(const float* __restrict__ qi, const float* __restrict__ ki,
                         const float* __restrict__ vi,
                         const unsigned short* __restrict__ wq,
                         const unsigned short* __restrict__ wk,
                         const unsigned short* __restrict__ wv,
                         unsigned short* __restrict__ qh,
                         unsigned short* __restrict__ kh,
                         unsigned short* __restrict__ vt) {
  const int z = blockIdx.z;
  const float* X = (z == 0) ? qi : (z == 1) ? ki : vi;
  const unsigned short* W = (z == 0) ? wq : (z == 1) ? wk : wv;
  unsigned short* O = (z == 0) ? qh : (z == 1) ? kh : vt;

  __shared__ unsigned short lds_a[128 * 40];   // padded rows (reg-staged)
  __shared__ unsigned short lds_b[128 * 32];   // linear (global_load_lds)

  const int tid = threadIdx.x;
  const int wave = tid >> 6, lane = tid & 63;
  const int wm = wave >> 1, wn = wave & 1;
  const int lr = lane & 15, lg = lane >> 4;
  const int m0 = blockIdx.y * 128, n0 = blockIdx.x * 128;

  const int ar = tid >> 1;           // A staging row
  const int ac = (tid & 1) * 16;     // A staging col (floats)

  f32x4 acc[4][4] = {};

  for (int k0 = 0; k0 < N_D; k0 += 32) {
    __syncthreads();
    // stage B via async copy (2 x 16B per thread)
#pragma unroll
    for (int it = 0; it < 2; ++it) {
      int c = it * 256 + tid;
      int row = c >> 2;
      int wcs = (c & 3) * 8;
      gll16(&W[(size_t)(n0 + row) * N_D + k0 + wcs], &lds_b[c * 8]);
    }
    // stage A: fp32 -> bf16
    {
      const float* src = X + (size_t)(m0 + ar) * N_D + k0 + ac;
      float4 f0 = ((const float4*)src)[0];
      float4 f1 = ((const float4*)src)[1];
      float4 f2 = ((const float4*)src)[2];
      float4 f3 = ((const float4*)src)[3];
      bf16x8 p0, p1;
      p0[0]=(short)f2bf(f0.x); p0[1]=(short)f2bf(f0.y); p0[2]=(short)f2bf(f0.z); p0[3]=(short)f2bf(f0.w);
      p0[4]=(short)f2bf(f1.x); p0[5]=(short)f2bf(f1.y); p0[6]=(short)f2bf(f1.z); p0[7]=(short)f2bf(f1.w);
      p1[0]=(short)f2bf(f2.x); p1[1]=(short)f2bf(f2.y); p1[2]=(short)f2bf(f2.z); p1[3]=(short)f2bf(f2.w);
      p1[4]=(short)f2bf(f3.x); p1[5]=(short)f2bf(f3.y); p1[6]=(short)f2bf(f3.z); p1[7]=(short)f2bf(f3.w);
      *(bf16x8*)&lds_a[ar * 40 + ac]     = p0;
      *(bf16x8*)&lds_a[ar * 40 + ac + 8] = p1;
    }
    __syncthreads();

    bf16x8 af[4], bfr[4];
#pragma unroll
    for (int m = 0; m < 4; ++m)
      af[m] = *(bf16x8*)&lds_a[(wm * 64 + m * 16 + lr) * 40 + lg * 8];
#pragma unroll
    for (int n = 0; n < 4; ++n)
      bfr[n] = *(bf16x8*)&lds_b[(wn * 64 + n * 16 + lr) * 32 + lg * 8];
#pragma unroll
    for (int m = 0; m < 4; ++m)
#pragma unroll
      for (int n = 0; n < 4; ++n)
        acc[m][n] = __builtin_amdgcn_mfma_f32_16x16x32_bf16(af[m], bfr[n], acc[m][n], 0, 0, 0);
  }

  // epilogue
#pragma unroll
  for (int m = 0; m < 4; ++m)
#pragma unroll
    for (int n = 0; n < 4; ++n)
#pragma unroll
      for (int r = 0; r < 4; ++r) {
        int row = m0 + wm * 64 + m * 16 + lg * 4 + r;   // token (b*T+t)
        int col = n0 + wn * 64 + n * 16 + lr;           // feature
        int b = row >> 11, t = row & (N_T - 1);
        int hh = col >> 6, dh = col & 63;
        unsigned short val = f2bf(acc[m][n][r]);
        if (z < 2)
          O[(((size_t)(b * N_H + hh)) * N_T + t) * N_DH + dh] = val;
        else
          O[(((size_t)(b * N_H + hh)) * N_DH + dh) * N_T + t] = val;
      }
}

// ------------------------------------------------------ output projection GEMM
__launch_bounds__(256, 2)
__global__ void proj_out(const unsigned short* __restrict__ A,
                         const unsigned short* __restrict__ W,
                         float* __restrict__ out) {
  __shared__ unsigned short lds_a[128 * 32];
  __shared__ unsigned short lds_b[128 * 32];

  const int tid = threadIdx.x;
  const int wave = tid >> 6, lane = tid & 63;
  const int wm = wave >> 1, wn = wave & 1;
  const int lr = lane & 15, lg = lane >> 4;
  const int m0 = blockIdx.y * 128, n0 = blockIdx.x * 128;

  f32x4 acc[4][4] = {};

  for (int k0 = 0; k0 < N_D; k0 += 32) {
    __syncthreads();
#pragma unroll
    for (int it = 0; it < 2; ++it) {
      int c = it * 256 + tid;
      int row = c >> 2;
      int wcs = (c & 3) * 8;
      gll16(&A[(size_t)(m0 + row) * N_D + k0 + wcs], &lds_a[c * 8]);
      gll16(&W[(size_t)(n0 + row) * N_D + k0 + wcs], &lds_b[c * 8]);
    }
    __syncthreads();

    bf16x8 af[4], bfr[4];
#pragma unroll
    for (int m = 0; m < 4; ++m)
      af[m] = *(bf16x8*)&lds_a[(wm * 64 + m * 16 + lr) * 32 + lg * 8];
#pragma unroll
    for (int n = 0; n < 4; ++n)
      bfr[n] = *(bf16x8*)&lds_b[(wn * 64 + n * 16 + lr) * 32 + lg * 8];
#pragma unroll
    for (int m = 0; m < 4; ++m)
#pragma unroll
      for (int n = 0; n < 4; ++n)
        acc[m][n] = __builtin_amdgcn_mfma_f32_16x16x32_bf16(af[m], bfr[n], acc[m][n], 0, 0, 0);
  }

#pragma unroll
  for (int m = 0; m < 4; ++m)
#pragma unroll
    for (int n = 0; n < 4; ++n)
#pragma unroll
      for (int r = 0; r < 4; ++r) {
        int row = m0 + wm * 64 + m * 16 + lg * 4 + r;
        int col = n0 + wn * 64 + n * 16 + lr;
        out[(size_t)row * N_D + col] = acc[m][n][r];
      }
}

// ----------------------------------------------------------- flash attention
// Block: one (b,h), processes q-tiles {px, 31-px} (balanced causal pairing).
// 4 waves x 16 q-rows. K and V^T staged via global_load_lds with XOR swizzle.
__launch_bounds__(256, 4)
__global__ void attn(const unsigned short* __restrict__ qh,
                     const unsigned short* __restrict__ kh,
                     const unsigned short* __restrict__ vt,
                     unsigned short* __restrict__ att) {
  __shared__ unsigned short k_lds[64 * 64];   // [key][d], rows XOR-swizzled
  __shared__ unsigned short v_lds[64 * 64];   // [d][key], rows XOR-swizzled
  __shared__ unsigned short p_lds[64 * 68];   // stride 68 (conflict-free)

  const int tid = threadIdx.x;
  const int wave = tid >> 6, lane = tid & 63;
  const int lr = lane & 15, lg = lane >> 4;
  const int bh = blockIdx.y;
  const size_t base = (size_t)bh * N_T * N_DH;
  const unsigned short* Q = qh + base;
  const unsigned short* K = kh + base;
  const unsigned short* V = vt + base;       // [DH][T]
  const int b = bh >> 4, h = bh & 15;
  const int sw = (lr & 7) << 4;              // read-side swizzle (bytes)

  for (int half = 0; half < 2; ++half) {
    const int qt = half ? (31 - (int)blockIdx.x) : (int)blockIdx.x;
    const int q0 = qt * 64;

    bf16x8 aq[2];
    {
      const int qrow = q0 + wave * 16 + lr;
      aq[0] = *(const bf16x8*)&Q[(size_t)qrow * N_DH + lg * 8];
      aq[1] = *(const bf16x8*)&Q[(size_t)qrow * N_DH + lg * 8 + 32];
    }

    float m_r[4], l_r[4];
    f32x4 o_acc[4] = {};
#pragma unroll
    for (int r = 0; r < 4; ++r) { m_r[r] = -INFINITY; l_r[r] = 0.f; }

    for (int kt = 0; kt <= qt; ++kt) {
      const int k0 = kt * 64;
      __syncthreads();     // previous tile fully consumed
      // stage K [64 key][64 d] and V^T [64 d][64 key], swizzled source
#pragma unroll
      for (int it = 0; it < 2; ++it) {
        int c = it * 256 + tid;
        int row = c >> 3;
        int sb = ((c & 7) * 16) ^ ((row & 7) << 4);   // bytes within 128B row
        gll16(&K[(size_t)(k0 + row) * N_DH + (sb >> 1)], &k_lds[c * 8]);
        gll16(&V[(size_t)row * N_T + k0 + (sb >> 1)], &v_lds[c * 8]);
      }
      __syncthreads();     // drains vmcnt -> tiles ready

      // S = Q @ K^T  (16 q-rows x 64 keys per wave)
      f32x4 s[4] = {};
#pragma unroll
      for (int n = 0; n < 4; ++n) {
        const int rb = (n * 16 + lr) * 64;
        bf16x8 kb0 = *(bf16x8*)&k_lds[rb + (((lg * 16) ^ sw) >> 1)];
        bf16x8 kb1 = *(bf16x8*)&k_lds[rb + (((lg * 16 + 64) ^ sw) >> 1)];
        s[n] = __builtin_amdgcn_mfma_f32_16x16x32_bf16(aq[0], kb0, s[n], 0, 0, 0);
        s[n] = __builtin_amdgcn_mfma_f32_16x16x32_bf16(aq[1], kb1, s[n], 0, 0, 0);
      }

      // scale + causal mask + online softmax
      float pv[4][4], mrow[4];
#pragma unroll
      for (int r = 0; r < 4; ++r) mrow[r] = -INFINITY;
#pragma unroll
      for (int n = 0; n < 4; ++n)
#pragma unroll
        for (int r = 0; r < 4; ++r) {
          float val = s[n][r] * 0.125f;
          int key = k0 + n * 16 + lr;
          int qr = q0 + wave * 16 + lg * 4 + r;
          if (key > qr) val = -INFINITY;
          pv[n][r] = val;
          mrow[r] = fmaxf(mrow[r], val);
        }
#pragma unroll
      for (int off = 1; off < 16; off <<= 1)
#pragma unroll
        for (int r = 0; r < 4; ++r) mrow[r] = fmaxf(mrow[r], __shfl_xor(mrow[r], off));

      float al[4];
#pragma unroll
      for (int r = 0; r < 4; ++r) {
        float mn = fmaxf(m_r[r], mrow[r]);
        al[r] = __expf(m_r[r] - mn);
        m_r[r] = mn;
      }
      float rs[4] = {0.f, 0.f, 0.f, 0.f};
#pragma unroll
      for (int n = 0; n < 4; ++n)
#pragma unroll
        for (int r = 0; r < 4; ++r) {
          float p = __expf(pv[n][r] - m_r[r]);
          pv[n][r] = p;
          rs[r] += p;
        }
#pragma unroll
      for (int off = 1; off < 16; off <<= 1)
#pragma unroll
        for (int r = 0; r < 4; ++r) rs[r] += __shfl_xor(rs[r], off);
#pragma unroll
      for (int r = 0; r < 4; ++r) l_r[r] = l_r[r] * al[r] + rs[r];
#pragma unroll
      for (int nd = 0; nd < 4; ++nd)
#pragma unroll
        for (int r = 0; r < 4; ++r) o_acc[nd][r] *= al[r];

      // P -> wave-private LDS rows (C-layout -> A-layout)
#pragma unroll
      for (int n = 0; n < 4; ++n)
#pragma unroll
        for (int r = 0; r < 4; ++r)
          p_lds[(wave * 16 + lg * 4 + r) * 68 + n * 16 + lr] = f2bf(pv[n][r]);

      // O += P @ V
#pragma unroll
      for (int kk = 0; kk < 2; ++kk) {
        bf16x8 pa = *(bf16x8*)&p_lds[(wave * 16 + lr) * 68 + lg * 8 + kk * 32];
#pragma unroll
        for (int nd = 0; nd < 4; ++nd) {
          const int rb = (nd * 16 + lr) * 64;
          bf16x8 vb = *(bf16x8*)&v_lds[rb + (((lg * 16 + kk * 64) ^ sw) >> 1)];
          o_acc[nd] = __builtin_amdgcn_mfma_f32_16x16x32_bf16(pa, vb, o_acc[nd], 0, 0, 0);
        }
      }
    }

    // epilogue: att[b, t, h*64+d] bf16
    float inv[4];
#pragma unroll
    for (int r = 0; r < 4; ++r) inv[r] = 1.0f / l_r[r];
#pragma unroll
    for (int nd = 0; nd < 4; ++nd)
#pragma unroll
      for (int r = 0; r < 4; ++r) {
        int t_row = q0 + wave * 16 + lg * 4 + r;
        att[((size_t)(b * N_T + t_row)) * N_D + h * 64 + nd * 16 + lr] =
            f2bf(o_acc[nd][r] * inv[r]);
      }
  }
}

// ---------------------------------------------------------------------- launch
extern "C" void kernel_launch(void* const* d_in, const int* in_sizes, int n_in,
                              void* d_out, int out_size, void* d_ws, size_t ws_size,
                              hipStream_t stream) {
  (void)in_sizes; (void)n_in; (void)out_size; (void)ws_size;
  const float* q  = (const float*)d_in[0];
  const float* k  = (const float*)d_in[1];
  const float* v  = (const float*)d_in[2];
  const float* wq = (const float*)d_in[3];
  const float* wk = (const float*)d_in[4];
  const float* wv = (const float*)d_in[5];
  const float* wo = (const float*)d_in[6];
  float* out = (float*)d_out;

  char* ws = (char*)d_ws;
  const size_t W_ELEMS = (size_t)N_D * N_D;           // 1048576
  const size_t T_ELEMS = (size_t)N_B * N_T * N_D;     // 8388608
  unsigned short* wqb = (unsigned short*)ws;
  unsigned short* wkb = wqb + W_ELEMS;
  unsigned short* wvb = wkb + W_ELEMS;
  unsigned short* wob = wvb + W_ELEMS;
  unsigned short* qhb = wob + W_ELEMS;
  unsigned short* khb = qhb + T_ELEMS;
  unsigned short* vtb = khb + T_ELEMS;
  unsigned short* att = vtb + T_ELEMS;

  cast_w<<<dim3(512, 1, 4), 256, 0, stream>>>(wq, wk, wv, wo, wqb);
  proj_qkv<<<dim3(8, 64, 3), 256, 0, stream>>>(q, k, v, wqb, wkb, wvb, qhb, khb, vtb);
  attn<<<dim3(16, N_B * N_H), 256, 0, stream>>>(qhb, khb, vtb, att);
  proj_out<<<dim3(8, 64), 256, 0, stream>>>(att, wob, out);
}

// Round 3
// 248.762 us; speedup vs baseline: 2.0661x; 1.1487x over previous
//
#include <hip/hip_runtime.h>
#include <hip/hip_bf16.h>

typedef short bf16x8 __attribute__((ext_vector_type(8)));
typedef float f32x4 __attribute__((ext_vector_type(4)));

#define N_B 4
#define N_T 2048
#define N_D 1024
#define N_H 16
#define N_DH 64

__device__ __forceinline__ unsigned short f2bf(float f) {
  union { float f; unsigned int u; } c; c.f = f;
  unsigned int u = c.u;
  return (unsigned short)((u + 0x7FFFu + ((u >> 16) & 1u)) >> 16);
}

// async global->LDS, 16B per lane (dest linear: wave base + lane*16)
__device__ __forceinline__ void gll16(const unsigned short* g, unsigned short* l) {
  __builtin_amdgcn_global_load_lds(
      (const __attribute__((address_space(1))) unsigned int*)(const void*)g,
      (__attribute__((address_space(3))) unsigned int*)(void*)l, 16, 0, 0);
}

// --------------------------------------------------- cast fp32 -> bf16 (7 arrays)
__global__ void cast_all(const float* __restrict__ wq, const float* __restrict__ wk,
                         const float* __restrict__ wv, const float* __restrict__ wo,
                         const float* __restrict__ q, const float* __restrict__ k,
                         const float* __restrict__ v,
                         unsigned short* __restrict__ ws) {
  const int z = blockIdx.z;
  const float* srcs[7] = {wq, wk, wv, wo, q, k, v};
  const int size = (z < 4) ? (N_D * N_D) : (N_B * N_T * N_D);
  const size_t off = (z < 4) ? (size_t)z * (N_D * N_D)
                             : (size_t)4 * (N_D * N_D) + (size_t)(z - 4) * (N_B * N_T * N_D);
  const int i = (blockIdx.x * 256 + threadIdx.x) * 8;
  if (i >= size) return;
  const float* src = srcs[z];
  float4 a = *(const float4*)(src + i);
  float4 b = *(const float4*)(src + i + 4);
  bf16x8 p;
  p[0] = (short)f2bf(a.x); p[1] = (short)f2bf(a.y);
  p[2] = (short)f2bf(a.z); p[3] = (short)f2bf(a.w);
  p[4] = (short)f2bf(b.x); p[5] = (short)f2bf(b.y);
  p[6] = (short)f2bf(b.z); p[7] = (short)f2bf(b.w);
  *(bf16x8*)(ws + off + i) = p;
}

// --------------------------------------------------------- qkv projection GEMM
// y = x @ W.T, all bf16. BK=64, st-swizzled LDS, global_load_lds staging.
// q,k outputs: [B,H,T,DH] ; v output: TRANSPOSED [B,H,DH,T].
__launch_bounds__(256, 2)
__global__ void proj_qkv(const unsigned short* __restrict__ qb,
                         const unsigned short* __restrict__ kb,
                         const unsigned short* __restrict__ vb,
                         const unsigned short* __restrict__ wq,
                         const unsigned short* __restrict__ wk,
                         const unsigned short* __restrict__ wv,
                         unsigned short* __restrict__ qh,
                         unsigned short* __restrict__ kh,
                         unsigned short* __restrict__ vt) {
  const int z = blockIdx.z;
  const unsigned short* X = (z == 0) ? qb : (z == 1) ? kb : vb;
  const unsigned short* W = (z == 0) ? wq : (z == 1) ? wk : wv;
  unsigned short* O = (z == 0) ? qh : (z == 1) ? kh : vt;

  __shared__ unsigned short lds_a[128 * 64];
  __shared__ unsigned short lds_b[128 * 64];

  const int tid = threadIdx.x;
  const int wave = tid >> 6, lane = tid & 63;
  const int wm = wave >> 1, wn = wave & 1;
  const int lr = lane & 15, lg = lane >> 4;
  // XCD-chunked swizzle: XCD x -> m-panels [8x,8x+8), all n (A+W chunk fits L2)
  const int orig = blockIdx.y * 8 + blockIdx.x;
  const int swz = (orig & 7) * 64 + (orig >> 3);
  const int m0 = (swz >> 3) * 128, n0 = (swz & 7) * 128;
  const int sw = (lr & 7) << 4;   // read-side swizzle (bytes)

  f32x4 acc[4][4] = {};

  for (int k0 = 0; k0 < N_D; k0 += 64) {
    __syncthreads();
#pragma unroll
    for (int it = 0; it < 4; ++it) {
      int c = it * 256 + tid;
      int row = c >> 3;
      int sb = ((c & 7) * 16) ^ ((row & 7) << 4);   // bytes within 128B row
      gll16(&X[(size_t)(m0 + row) * N_D + k0 + (sb >> 1)], &lds_a[c * 8]);
      gll16(&W[(size_t)(n0 + row) * N_D + k0 + (sb >> 1)], &lds_b[c * 8]);
    }
    __syncthreads();

#pragma unroll
    for (int kk = 0; kk < 2; ++kk) {
      bf16x8 af[4], bfr[4];
      const int cb = (lg * 16 + kk * 64);
#pragma unroll
      for (int m = 0; m < 4; ++m)
        af[m] = *(bf16x8*)&lds_a[(wm * 64 + m * 16 + lr) * 64 + ((cb ^ sw) >> 1)];
#pragma unroll
      for (int n = 0; n < 4; ++n)
        bfr[n] = *(bf16x8*)&lds_b[(wn * 64 + n * 16 + lr) * 64 + ((cb ^ sw) >> 1)];
#pragma unroll
      for (int m = 0; m < 4; ++m)
#pragma unroll
        for (int n = 0; n < 4; ++n)
          acc[m][n] = __builtin_amdgcn_mfma_f32_16x16x32_bf16(af[m], bfr[n], acc[m][n], 0, 0, 0);
    }
  }

  // epilogue
#pragma unroll
  for (int m = 0; m < 4; ++m)
#pragma unroll
    for (int n = 0; n < 4; ++n)
#pragma unroll
      for (int r = 0; r < 4; ++r) {
        int row = m0 + wm * 64 + m * 16 + lg * 4 + r;   // token (b*T+t)
        int col = n0 + wn * 64 + n * 16 + lr;           // feature
        int b = row >> 11, t = row & (N_T - 1);
        int hh = col >> 6, dh = col & 63;
        unsigned short val = f2bf(acc[m][n][r]);
        if (z < 2)
          O[(((size_t)(b * N_H + hh)) * N_T + t) * N_DH + dh] = val;
        else
          O[(((size_t)(b * N_H + hh)) * N_DH + dh) * N_T + t] = val;
      }
}

// ------------------------------------------------------ output projection GEMM
__launch_bounds__(256, 2)
__global__ void proj_out(const unsigned short* __restrict__ A,
                         const unsigned short* __restrict__ W,
                         float* __restrict__ out) {
  __shared__ unsigned short lds_a[128 * 64];
  __shared__ unsigned short lds_b[128 * 64];

  const int tid = threadIdx.x;
  const int wave = tid >> 6, lane = tid & 63;
  const int wm = wave >> 1, wn = wave & 1;
  const int lr = lane & 15, lg = lane >> 4;
  const int orig = blockIdx.y * 8 + blockIdx.x;
  const int swz = (orig & 7) * 64 + (orig >> 3);
  const int m0 = (swz >> 3) * 128, n0 = (swz & 7) * 128;
  const int sw = (lr & 7) << 4;

  f32x4 acc[4][4] = {};

  for (int k0 = 0; k0 < N_D; k0 += 64) {
    __syncthreads();
#pragma unroll
    for (int it = 0; it < 4; ++it) {
      int c = it * 256 + tid;
      int row = c >> 3;
      int sb = ((c & 7) * 16) ^ ((row & 7) << 4);
      gll16(&A[(size_t)(m0 + row) * N_D + k0 + (sb >> 1)], &lds_a[c * 8]);
      gll16(&W[(size_t)(n0 + row) * N_D + k0 + (sb >> 1)], &lds_b[c * 8]);
    }
    __syncthreads();

#pragma unroll
    for (int kk = 0; kk < 2; ++kk) {
      bf16x8 af[4], bfr[4];
      const int cb = (lg * 16 + kk * 64);
#pragma unroll
      for (int m = 0; m < 4; ++m)
        af[m] = *(bf16x8*)&lds_a[(wm * 64 + m * 16 + lr) * 64 + ((cb ^ sw) >> 1)];
#pragma unroll
      for (int n = 0; n < 4; ++n)
        bfr[n] = *(bf16x8*)&lds_b[(wn * 64 + n * 16 + lr) * 64 + ((cb ^ sw) >> 1)];
#pragma unroll
      for (int m = 0; m < 4; ++m)
#pragma unroll
        for (int n = 0; n < 4; ++n)
          acc[m][n] = __builtin_amdgcn_mfma_f32_16x16x32_bf16(af[m], bfr[n], acc[m][n], 0, 0, 0);
    }
  }

#pragma unroll
  for (int m = 0; m < 4; ++m)
#pragma unroll
    for (int n = 0; n < 4; ++n)
#pragma unroll
      for (int r = 0; r < 4; ++r) {
        int row = m0 + wm * 64 + m * 16 + lg * 4 + r;
        int col = n0 + wn * 64 + n * 16 + lr;
        out[(size_t)row * N_D + col] = acc[m][n][r];
      }
}

// ----------------------------------------------------------- flash attention
__launch_bounds__(256, 4)
__global__ void attn(const unsigned short* __restrict__ qh,
                     const unsigned short* __restrict__ kh,
                     const unsigned short* __restrict__ vt,
                     unsigned short* __restrict__ att) {
  __shared__ unsigned short k_lds[64 * 64];   // [key][d], rows XOR-swizzled
  __shared__ unsigned short v_lds[64 * 64];   // [d][key], rows XOR-swizzled
  __shared__ unsigned short p_lds[64 * 68];   // stride 68 (conflict-free)

  const int tid = threadIdx.x;
  const int wave = tid >> 6, lane = tid & 63;
  const int lr = lane & 15, lg = lane >> 4;
  const int bh = blockIdx.y;
  const size_t base = (size_t)bh * N_T * N_DH;
  const unsigned short* Q = qh + base;
  const unsigned short* K = kh + base;
  const unsigned short* V = vt + base;       // [DH][T]
  const int b = bh >> 4, h = bh & 15;
  const int sw = (lr & 7) << 4;

  for (int half = 0; half < 2; ++half) {
    const int qt = half ? (31 - (int)blockIdx.x) : (int)blockIdx.x;
    const int q0 = qt * 64;

    bf16x8 aq[2];
    {
      const int qrow = q0 + wave * 16 + lr;
      aq[0] = *(const bf16x8*)&Q[(size_t)qrow * N_DH + lg * 8];
      aq[1] = *(const bf16x8*)&Q[(size_t)qrow * N_DH + lg * 8 + 32];
    }

    float m_r[4], l_r[4];
    f32x4 o_acc[4] = {};
#pragma unroll
    for (int r = 0; r < 4; ++r) { m_r[r] = -INFINITY; l_r[r] = 0.f; }

    for (int kt = 0; kt <= qt; ++kt) {
      const int k0 = kt * 64;
      __syncthreads();
#pragma unroll
      for (int it = 0; it < 2; ++it) {
        int c = it * 256 + tid;
        int row = c >> 3;
        int sb = ((c & 7) * 16) ^ ((row & 7) << 4);
        gll16(&K[(size_t)(k0 + row) * N_DH + (sb >> 1)], &k_lds[c * 8]);
        gll16(&V[(size_t)row * N_T + k0 + (sb >> 1)], &v_lds[c * 8]);
      }
      __syncthreads();

      f32x4 s[4] = {};
#pragma unroll
      for (int n = 0; n < 4; ++n) {
        const int rb = (n * 16 + lr) * 64;
        bf16x8 kb0 = *(bf16x8*)&k_lds[rb + (((lg * 16) ^ sw) >> 1)];
        bf16x8 kb1 = *(bf16x8*)&k_lds[rb + (((lg * 16 + 64) ^ sw) >> 1)];
        s[n] = __builtin_amdgcn_mfma_f32_16x16x32_bf16(aq[0], kb0, s[n], 0, 0, 0);
        s[n] = __builtin_amdgcn_mfma_f32_16x16x32_bf16(aq[1], kb1, s[n], 0, 0, 0);
      }

      float pv[4][4], mrow[4];
#pragma unroll
      for (int r = 0; r < 4; ++r) mrow[r] = -INFINITY;
#pragma unroll
      for (int n = 0; n < 4; ++n)
#pragma unroll
        for (int r = 0; r < 4; ++r) {
          float val = s[n][r] * 0.125f;
          int key = k0 + n * 16 + lr;
          int qr = q0 + wave * 16 + lg * 4 + r;
          if (key > qr) val = -INFINITY;
          pv[n][r] = val;
          mrow[r] = fmaxf(mrow[r], val);
        }
#pragma unroll
      for (int off = 1; off < 16; off <<= 1)
#pragma unroll
        for (int r = 0; r < 4; ++r) mrow[r] = fmaxf(mrow[r], __shfl_xor(mrow[r], off));

      float al[4];
#pragma unroll
      for (int r = 0; r < 4; ++r) {
        float mn = fmaxf(m_r[r], mrow[r]);
        al[r] = __expf(m_r[r] - mn);
        m_r[r] = mn;
      }
      float rs[4] = {0.f, 0.f, 0.f, 0.f};
#pragma unroll
      for (int n = 0; n < 4; ++n)
#pragma unroll
        for (int r = 0; r < 4; ++r) {
          float p = __expf(pv[n][r] - m_r[r]);
          pv[n][r] = p;
          rs[r] += p;
        }
#pragma unroll
      for (int off = 1; off < 16; off <<= 1)
#pragma unroll
        for (int r = 0; r < 4; ++r) rs[r] += __shfl_xor(rs[r], off);
#pragma unroll
      for (int r = 0; r < 4; ++r) l_r[r] = l_r[r] * al[r] + rs[r];
#pragma unroll
      for (int nd = 0; nd < 4; ++nd)
#pragma unroll
        for (int r = 0; r < 4; ++r) o_acc[nd][r] *= al[r];

#pragma unroll
      for (int n = 0; n < 4; ++n)
#pragma unroll
        for (int r = 0; r < 4; ++r)
          p_lds[(wave * 16 + lg * 4 + r) * 68 + n * 16 + lr] = f2bf(pv[n][r]);

#pragma unroll
      for (int kk = 0; kk < 2; ++kk) {
        bf16x8 pa = *(bf16x8*)&p_lds[(wave * 16 + lr) * 68 + lg * 8 + kk * 32];
#pragma unroll
        for (int nd = 0; nd < 4; ++nd) {
          const int rb = (nd * 16 + lr) * 64;
          bf16x8 vb = *(bf16x8*)&v_lds[rb + (((lg * 16 + kk * 64) ^ sw) >> 1)];
          o_acc[nd] = __builtin_amdgcn_mfma_f32_16x16x32_bf16(pa, vb, o_acc[nd], 0, 0, 0);
        }
      }
    }

    float inv[4];
#pragma unroll
    for (int r = 0; r < 4; ++r) inv[r] = 1.0f / l_r[r];
#pragma unroll
    for (int nd = 0; nd < 4; ++nd)
#pragma unroll
      for (int r = 0; r < 4; ++r) {
        int t_row = q0 + wave * 16 + lg * 4 + r;
        att[((size_t)(b * N_T + t_row)) * N_D + h * 64 + nd * 16 + lr] =
            f2bf(o_acc[nd][r] * inv[r]);
      }
  }
}

// ---------------------------------------------------------------------- launch
extern "C" void kernel_launch(void* const* d_in, const int* in_sizes, int n_in,
                              void* d_out, int out_size, void* d_ws, size_t ws_size,
                              hipStream_t stream) {
  (void)in_sizes; (void)n_in; (void)out_size; (void)ws_size;
  const float* q  = (const float*)d_in[0];
  const float* k  = (const float*)d_in[1];
  const float* v  = (const float*)d_in[2];
  const float* wq = (const float*)d_in[3];
  const float* wk = (const float*)d_in[4];
  const float* wv = (const float*)d_in[5];
  const float* wo = (const float*)d_in[6];
  float* out = (float*)d_out;

  unsigned short* ws = (unsigned short*)d_ws;
  const size_t W_ELEMS = (size_t)N_D * N_D;           // 1M
  const size_t T_ELEMS = (size_t)N_B * N_T * N_D;     // 8M
  unsigned short* wqb = ws;                 // 4 weights at 0..4M
  unsigned short* wkb = wqb + W_ELEMS;
  unsigned short* wvb = wkb + W_ELEMS;
  unsigned short* wob = wvb + W_ELEMS;
  unsigned short* qb  = wob + W_ELEMS;      // bf16 inputs 4M..28M
  unsigned short* kb  = qb + T_ELEMS;
  unsigned short* vb  = kb + T_ELEMS;
  unsigned short* qhb = vb + T_ELEMS;       // 28M..52M
  unsigned short* khb = qhb + T_ELEMS;
  unsigned short* vtb = khb + T_ELEMS;
  unsigned short* att = qb;                 // alias: qb dead after proj_qkv

  cast_all<<<dim3(4096, 1, 7), 256, 0, stream>>>(wq, wk, wv, wo, q, k, v, ws);
  proj_qkv<<<dim3(8, 64, 3), 256, 0, stream>>>(qb, kb, vb, wqb, wkb, wvb, qhb, khb, vtb);
  attn<<<dim3(16, N_B * N_H), 256, 0, stream>>>(qhb, khb, vtb, att);
  proj_out<<<dim3(8, 64), 256, 0, stream>>>(att, wob, out);
}

// Round 4
// 206.823 us; speedup vs baseline: 2.4851x; 1.2028x over previous
//
#include <hip/hip_runtime.h>
#include <hip/hip_bf16.h>

typedef short bf16x8 __attribute__((ext_vector_type(8)));
typedef float f32x4 __attribute__((ext_vector_type(4)));

#define N_B 4
#define N_T 2048
#define N_D 1024
#define N_H 16
#define N_DH 64

// 0.125 * log2(e): folds attention scale + exp->exp2 conversion into Q proj
#define Q_SCALE 0.18033688011112042f

__device__ __forceinline__ unsigned short f2bf(float f) {
  union { float f; unsigned int u; } c; c.f = f;
  unsigned int u = c.u;
  return (unsigned short)((u + 0x7FFFu + ((u >> 16) & 1u)) >> 16);
}

// async global->LDS, 16B per lane (dest linear: wave base + lane*16)
__device__ __forceinline__ void gll16(const unsigned short* g, unsigned short* l) {
  __builtin_amdgcn_global_load_lds(
      (const __attribute__((address_space(1))) unsigned int*)(const void*)g,
      (__attribute__((address_space(3))) unsigned int*)(void*)l, 16, 0, 0);
}

// --------------------------------------------------- cast fp32 -> bf16 (7 arrays)
__global__ void cast_all(const float* __restrict__ wq, const float* __restrict__ wk,
                         const float* __restrict__ wv, const float* __restrict__ wo,
                         const float* __restrict__ q, const float* __restrict__ k,
                         const float* __restrict__ v,
                         unsigned short* __restrict__ ws) {
  const int z = blockIdx.z;
  const float* srcs[7] = {wq, wk, wv, wo, q, k, v};
  const int size = (z < 4) ? (N_D * N_D) : (N_B * N_T * N_D);
  const size_t off = (z < 4) ? (size_t)z * (N_D * N_D)
                             : (size_t)4 * (N_D * N_D) + (size_t)(z - 4) * (N_B * N_T * N_D);
  const int i = (blockIdx.x * 256 + threadIdx.x) * 8;
  if (i >= size) return;
  const float* src = srcs[z];
  float4 a = *(const float4*)(src + i);
  float4 b = *(const float4*)(src + i + 4);
  bf16x8 p;
  p[0] = (short)f2bf(a.x); p[1] = (short)f2bf(a.y);
  p[2] = (short)f2bf(a.z); p[3] = (short)f2bf(a.w);
  p[4] = (short)f2bf(b.x); p[5] = (short)f2bf(b.y);
  p[6] = (short)f2bf(b.z); p[7] = (short)f2bf(b.w);
  *(bf16x8*)(ws + off + i) = p;
}

// --------------------------------------------------------- qkv projection GEMM
// y = x @ W.T, all bf16. BK=64, st-swizzled LDS, global_load_lds staging.
// q output: [B,H,T,DH] scaled by Q_SCALE ; k: [B,H,T,DH] ; v: TRANSPOSED [B,H,DH,T].
__launch_bounds__(256, 2)
__global__ void proj_qkv(const unsigned short* __restrict__ qb,
                         const unsigned short* __restrict__ kb,
                         const unsigned short* __restrict__ vb,
                         const unsigned short* __restrict__ wq,
                         const unsigned short* __restrict__ wk,
                         const unsigned short* __restrict__ wv,
                         unsigned short* __restrict__ qh,
                         unsigned short* __restrict__ kh,
                         unsigned short* __restrict__ vt) {
  const int z = blockIdx.z;
  const unsigned short* X = (z == 0) ? qb : (z == 1) ? kb : vb;
  const unsigned short* W = (z == 0) ? wq : (z == 1) ? wk : wv;
  unsigned short* O = (z == 0) ? qh : (z == 1) ? kh : vt;

  __shared__ unsigned short lds_a[128 * 64];
  __shared__ unsigned short lds_b[128 * 64];

  const int tid = threadIdx.x;
  const int wave = tid >> 6, lane = tid & 63;
  const int wm = wave >> 1, wn = wave & 1;
  const int lr = lane & 15, lg = lane >> 4;
  const int orig = blockIdx.y * 8 + blockIdx.x;
  const int swz = (orig & 7) * 64 + (orig >> 3);
  const int m0 = (swz >> 3) * 128, n0 = (swz & 7) * 128;
  const int sw = (lr & 7) << 4;

  f32x4 acc[4][4] = {};

  for (int k0 = 0; k0 < N_D; k0 += 64) {
    __syncthreads();
#pragma unroll
    for (int it = 0; it < 4; ++it) {
      int c = it * 256 + tid;
      int row = c >> 3;
      int sb = ((c & 7) * 16) ^ ((row & 7) << 4);
      gll16(&X[(size_t)(m0 + row) * N_D + k0 + (sb >> 1)], &lds_a[c * 8]);
      gll16(&W[(size_t)(n0 + row) * N_D + k0 + (sb >> 1)], &lds_b[c * 8]);
    }
    __syncthreads();

#pragma unroll
    for (int kk = 0; kk < 2; ++kk) {
      bf16x8 af[4], bfr[4];
      const int cb = (lg * 16 + kk * 64);
#pragma unroll
      for (int m = 0; m < 4; ++m)
        af[m] = *(bf16x8*)&lds_a[(wm * 64 + m * 16 + lr) * 64 + ((cb ^ sw) >> 1)];
#pragma unroll
      for (int n = 0; n < 4; ++n)
        bfr[n] = *(bf16x8*)&lds_b[(wn * 64 + n * 16 + lr) * 64 + ((cb ^ sw) >> 1)];
#pragma unroll
      for (int m = 0; m < 4; ++m)
#pragma unroll
        for (int n = 0; n < 4; ++n)
          acc[m][n] = __builtin_amdgcn_mfma_f32_16x16x32_bf16(af[m], bfr[n], acc[m][n], 0, 0, 0);
    }
  }

  const float osc = (z == 0) ? Q_SCALE : 1.0f;
#pragma unroll
  for (int m = 0; m < 4; ++m)
#pragma unroll
    for (int n = 0; n < 4; ++n)
#pragma unroll
      for (int r = 0; r < 4; ++r) {
        int row = m0 + wm * 64 + m * 16 + lg * 4 + r;   // token (b*T+t)
        int col = n0 + wn * 64 + n * 16 + lr;           // feature
        int b = row >> 11, t = row & (N_T - 1);
        int hh = col >> 6, dh = col & 63;
        unsigned short val = f2bf(acc[m][n][r] * osc);
        if (z < 2)
          O[(((size_t)(b * N_H + hh)) * N_T + t) * N_DH + dh] = val;
        else
          O[(((size_t)(b * N_H + hh)) * N_DH + dh) * N_T + t] = val;
      }
}

// ------------------------------------------------------ output projection GEMM
__launch_bounds__(256, 2)
__global__ void proj_out(const unsigned short* __restrict__ A,
                         const unsigned short* __restrict__ W,
                         float* __restrict__ out) {
  __shared__ unsigned short lds_a[128 * 64];
  __shared__ unsigned short lds_b[128 * 64];

  const int tid = threadIdx.x;
  const int wave = tid >> 6, lane = tid & 63;
  const int wm = wave >> 1, wn = wave & 1;
  const int lr = lane & 15, lg = lane >> 4;
  const int orig = blockIdx.y * 8 + blockIdx.x;
  const int swz = (orig & 7) * 64 + (orig >> 3);
  const int m0 = (swz >> 3) * 128, n0 = (swz & 7) * 128;
  const int sw = (lr & 7) << 4;

  f32x4 acc[4][4] = {};

  for (int k0 = 0; k0 < N_D; k0 += 64) {
    __syncthreads();
#pragma unroll
    for (int it = 0; it < 4; ++it) {
      int c = it * 256 + tid;
      int row = c >> 3;
      int sb = ((c & 7) * 16) ^ ((row & 7) << 4);
      gll16(&A[(size_t)(m0 + row) * N_D + k0 + (sb >> 1)], &lds_a[c * 8]);
      gll16(&W[(size_t)(n0 + row) * N_D + k0 + (sb >> 1)], &lds_b[c * 8]);
    }
    __syncthreads();

#pragma unroll
    for (int kk = 0; kk < 2; ++kk) {
      bf16x8 af[4], bfr[4];
      const int cb = (lg * 16 + kk * 64);
#pragma unroll
      for (int m = 0; m < 4; ++m)
        af[m] = *(bf16x8*)&lds_a[(wm * 64 + m * 16 + lr) * 64 + ((cb ^ sw) >> 1)];
#pragma unroll
      for (int n = 0; n < 4; ++n)
        bfr[n] = *(bf16x8*)&lds_b[(wn * 64 + n * 16 + lr) * 64 + ((cb ^ sw) >> 1)];
#pragma unroll
      for (int m = 0; m < 4; ++m)
#pragma unroll
        for (int n = 0; n < 4; ++n)
          acc[m][n] = __builtin_amdgcn_mfma_f32_16x16x32_bf16(af[m], bfr[n], acc[m][n], 0, 0, 0);
    }
  }

#pragma unroll
  for (int m = 0; m < 4; ++m)
#pragma unroll
    for (int n = 0; n < 4; ++n)
#pragma unroll
      for (int r = 0; r < 4; ++r) {
        int row = m0 + wm * 64 + m * 16 + lg * 4 + r;
        int col = n0 + wn * 64 + n * 16 + lr;
        out[(size_t)row * N_D + col] = acc[m][n][r];
      }
}

// ----------------------------------------------------------- flash attention
// Q pre-scaled by 0.125*log2(e) -> softmax in base-2. Double-buffered K/V,
// diagonal-only masking, defer-max (THR=8), l via MFMA row-sum, bf16-RTZ P.
__launch_bounds__(256, 4)
__global__ void attn(const unsigned short* __restrict__ qh,
                     const unsigned short* __restrict__ kh,
                     const unsigned short* __restrict__ vt,
                     unsigned short* __restrict__ att) {
  __shared__ unsigned short k_lds[2][64 * 64];  // [key][d], XOR-swizzled
  __shared__ unsigned short v_lds[2][64 * 64];  // [d][key], XOR-swizzled
  __shared__ unsigned short p_lds[64 * 64];     // XOR-swizzled

  const int tid = threadIdx.x;
  const int wave = tid >> 6, lane = tid & 63;
  const int lr = lane & 15, lg = lane >> 4;
  const int bh = blockIdx.y;
  const size_t base = (size_t)bh * N_T * N_DH;
  const unsigned short* Q = qh + base;
  const unsigned short* K = kh + base;
  const unsigned short* V = vt + base;          // [DH][T]
  const int b = bh >> 4, h = bh & 15;
  const int sw = (lr & 7) << 4;

  bf16x8 ones;
#pragma unroll
  for (int j = 0; j < 8; ++j) ones[j] = (short)0x3F80;

  auto stage = [&](int buf, int kt2) {
    const int kk0 = kt2 * 64;
#pragma unroll
    for (int it = 0; it < 2; ++it) {
      int c = it * 256 + tid;
      int row = c >> 3;
      int sb = ((c & 7) * 16) ^ ((row & 7) << 4);
      gll16(&K[(size_t)(kk0 + row) * N_DH + (sb >> 1)], &k_lds[buf][c * 8]);
      gll16(&V[(size_t)row * N_T + kk0 + (sb >> 1)], &v_lds[buf][c * 8]);
    }
  };

  for (int half = 0; half < 2; ++half) {
    const int qt = half ? (31 - (int)blockIdx.x) : (int)blockIdx.x;
    const int q0 = qt * 64;

    bf16x8 aq[2];
    {
      const int qrow = q0 + wave * 16 + lr;
      aq[0] = *(const bf16x8*)&Q[(size_t)qrow * N_DH + lg * 8];
      aq[1] = *(const bf16x8*)&Q[(size_t)qrow * N_DH + lg * 8 + 32];
    }

    float m_r[4], l_r[4];
    f32x4 o_acc[4] = {};
#pragma unroll
    for (int r = 0; r < 4; ++r) { m_r[r] = -INFINITY; l_r[r] = 0.f; }

    __syncthreads();          // previous half's last tile fully consumed
    stage(0, 0);              // prologue prefetch

    for (int kt = 0; kt <= qt; ++kt) {
      const int k0 = kt * 64;
      const int cur = kt & 1;
      __syncthreads();        // drains vmcnt -> buf[cur] ready
      if (kt < qt) stage(cur ^ 1, kt + 1);   // overlap next loads with compute

      // S = Q @ K^T (log2-scaled)
      f32x4 s4[4] = {};
#pragma unroll
      for (int n = 0; n < 4; ++n) {
        const int rb = (n * 16 + lr) * 64;
        bf16x8 kb0 = *(bf16x8*)&k_lds[cur][rb + (((lg * 16) ^ sw) >> 1)];
        bf16x8 kb1 = *(bf16x8*)&k_lds[cur][rb + (((lg * 16 + 64) ^ sw) >> 1)];
        s4[n] = __builtin_amdgcn_mfma_f32_16x16x32_bf16(aq[0], kb0, s4[n], 0, 0, 0);
        s4[n] = __builtin_amdgcn_mfma_f32_16x16x32_bf16(aq[1], kb1, s4[n], 0, 0, 0);
      }

      // causal mask: only the diagonal tile
      float pv[4][4];
      if (kt == qt) {
#pragma unroll
        for (int n = 0; n < 4; ++n)
#pragma unroll
          for (int r = 0; r < 4; ++r) {
            int key = k0 + n * 16 + lr;
            int qr = q0 + wave * 16 + lg * 4 + r;
            pv[n][r] = (key > qr) ? -INFINITY : s4[n][r];
          }
      } else {
#pragma unroll
        for (int n = 0; n < 4; ++n)
#pragma unroll
          for (int r = 0; r < 4; ++r) pv[n][r] = s4[n][r];
      }

      // defer-max: lane-local max, rescale only if it grew past THR=8
      float lm[4];
#pragma unroll
      for (int r = 0; r < 4; ++r)
        lm[r] = fmaxf(fmaxf(pv[0][r], pv[1][r]), fmaxf(pv[2][r], pv[3][r]));
      bool need = false;
#pragma unroll
      for (int r = 0; r < 4; ++r) need = need || (lm[r] > m_r[r] + 8.0f);
      float al[4];
      const bool doresc = (bool)__any((int)need);
      if (doresc) {
        float mrow[4];
#pragma unroll
        for (int r = 0; r < 4; ++r) mrow[r] = lm[r];
#pragma unroll
        for (int off = 1; off < 16; off <<= 1)
#pragma unroll
          for (int r = 0; r < 4; ++r) mrow[r] = fmaxf(mrow[r], __shfl_xor(mrow[r], off));
#pragma unroll
        for (int r = 0; r < 4; ++r) {
          float mn = fmaxf(m_r[r], mrow[r]);
          al[r] = exp2f(m_r[r] - mn);
          m_r[r] = mn;
        }
#pragma unroll
        for (int nd = 0; nd < 4; ++nd)
#pragma unroll
          for (int r = 0; r < 4; ++r) o_acc[nd][r] *= al[r];
      }

      // P = exp2(S - m), truncate to bf16, store swizzled (C-layout -> A-layout)
#pragma unroll
      for (int n = 0; n < 4; ++n)
#pragma unroll
        for (int r = 0; r < 4; ++r) {
          float p = exp2f(pv[n][r] - m_r[r]);
          union { float f; unsigned int u; } cu; cu.f = p;
          const int rloc = wave * 16 + lg * 4 + r;
          p_lds[rloc * 64 + ((n * 16 + lr) ^ (((lg * 4 + r) & 7) << 3))] =
              (unsigned short)(cu.u >> 16);
        }

      // O += P @ V ; l-contribution = P @ ones via MFMA (row-sum in C layout)
      f32x4 rs4 = {};
#pragma unroll
      for (int kk = 0; kk < 2; ++kk) {
        const int prow = wave * 16 + lr;
        bf16x8 pa = *(bf16x8*)&p_lds[prow * 64 + ((lg * 8 + kk * 32) ^ ((lr & 7) << 3))];
        rs4 = __builtin_amdgcn_mfma_f32_16x16x32_bf16(pa, ones, rs4, 0, 0, 0);
#pragma unroll
        for (int nd = 0; nd < 4; ++nd) {
          const int rb = (nd * 16 + lr) * 64;
          bf16x8 vb = *(bf16x8*)&v_lds[cur][rb + (((lg * 16 + kk * 64) ^ sw) >> 1)];
          o_acc[nd] = __builtin_amdgcn_mfma_f32_16x16x32_bf16(pa, vb, o_acc[nd], 0, 0, 0);
        }
      }
      if (doresc) {
#pragma unroll
        for (int r = 0; r < 4; ++r) l_r[r] = l_r[r] * al[r] + rs4[r];
      } else {
#pragma unroll
        for (int r = 0; r < 4; ++r) l_r[r] += rs4[r];
      }
    }

    float inv[4];
#pragma unroll
    for (int r = 0; r < 4; ++r) inv[r] = 1.0f / l_r[r];
#pragma unroll
    for (int nd = 0; nd < 4; ++nd)
#pragma unroll
      for (int r = 0; r < 4; ++r) {
        int t_row = q0 + wave * 16 + lg * 4 + r;
        att[((size_t)(b * N_T + t_row)) * N_D + h * 64 + nd * 16 + lr] =
            f2bf(o_acc[nd][r] * inv[r]);
      }
  }
}

// ---------------------------------------------------------------------- launch
extern "C" void kernel_launch(void* const* d_in, const int* in_sizes, int n_in,
                              void* d_out, int out_size, void* d_ws, size_t ws_size,
                              hipStream_t stream) {
  (void)in_sizes; (void)n_in; (void)out_size; (void)ws_size;
  const float* q  = (const float*)d_in[0];
  const float* k  = (const float*)d_in[1];
  const float* v  = (const float*)d_in[2];
  const float* wq = (const float*)d_in[3];
  const float* wk = (const float*)d_in[4];
  const float* wv = (const float*)d_in[5];
  const float* wo = (const float*)d_in[6];
  float* out = (float*)d_out;

  unsigned short* ws = (unsigned short*)d_ws;
  const size_t W_ELEMS = (size_t)N_D * N_D;           // 1M
  const size_t T_ELEMS = (size_t)N_B * N_T * N_D;     // 8M
  unsigned short* wqb = ws;                 // 4 weights
  unsigned short* wkb = wqb + W_ELEMS;
  unsigned short* wvb = wkb + W_ELEMS;
  unsigned short* wob = wvb + W_ELEMS;
  unsigned short* qb  = wob + W_ELEMS;      // bf16 inputs
  unsigned short* kb  = qb + T_ELEMS;
  unsigned short* vb  = kb + T_ELEMS;
  unsigned short* qhb = vb + T_ELEMS;
  unsigned short* khb = qhb + T_ELEMS;
  unsigned short* vtb = khb + T_ELEMS;
  unsigned short* att = qb;                 // alias: qb dead after proj_qkv

  cast_all<<<dim3(4096, 1, 7), 256, 0, stream>>>(wq, wk, wv, wo, q, k, v, ws);
  proj_qkv<<<dim3(8, 64, 3), 256, 0, stream>>>(qb, kb, vb, wqb, wkb, wvb, qhb, khb, vtb);
  attn<<<dim3(16, N_B * N_H), 256, 0, stream>>>(qhb, khb, vtb, att);
  proj_out<<<dim3(8, 64), 256, 0, stream>>>(att, wob, out);
}